// Round 5
// baseline (701.434 us; speedup 1.0000x reference)
//
#include <hip/hip_runtime.h>

// Linear attention (elu+1 feature map), B=4 S=4096 D=2048 H=16 dk=128.
// bf16 MFMA, fp32 accumulate.
// Round 5: fine-grained group-pipelined 256x256 GEMM — 4 LDS slots (32 KB =
// one kk-half of A+B), stage issued per-phase at the recycling barrier,
// counted vmcnt(8) steady state, 2 barriers/K-tile, packed row-pair LDS
// layout keeping the 8-quad XOR swizzle (0 bank conflicts).

#define D_MODEL 2048
#define SEQ     4096
#define BATCH   4
#define HEADS   16
#define DKH     128
#define M_TOK   16384   // BATCH*SEQ
#define NBH     64      // BATCH*HEADS

using frag8 = __attribute__((ext_vector_type(8))) short;   // 8 bf16 (4 VGPRs)
using f32x4 = __attribute__((ext_vector_type(4))) float;   // 4 fp32 acc

typedef __attribute__((address_space(1))) const unsigned int g_u32;
typedef __attribute__((address_space(3))) unsigned int       l_u32;

__device__ __forceinline__ unsigned short f2bf(float f) {
  unsigned u = __float_as_uint(f);
  u = u + 0x7fffu + ((u >> 16) & 1u);   // round-to-nearest-even
  return (unsigned short)(u >> 16);
}
__device__ __forceinline__ float bf2f(unsigned short h) {
  return __uint_as_float(((unsigned)h) << 16);
}

// ---- fp32 -> bf16 convert (vectorized) --------------------------------------
__global__ __launch_bounds__(256) void convert_f2bf_kernel(
    const float* __restrict__ in, unsigned short* __restrict__ out, int n4) {
  int i = blockIdx.x * 256 + threadIdx.x;
  if (i < n4) {
    float4 v = reinterpret_cast<const float4*>(in)[i];
    ushort4 o;
    o.x = f2bf(v.x); o.y = f2bf(v.y); o.z = f2bf(v.z); o.w = f2bf(v.w);
    reinterpret_cast<ushort4*>(out)[i] = o;
  }
}

// ============================================================================
// 256x256x(BK=64) group-pipelined GEMM, C = A(256xK)*B(256xK)^T, bf16 NT.
// 512 thr = 8 waves (2M x 4N); per-wave C = 128x64 = (2 MS-halves x 4m) x 4n.
// Group g = kk-half (g&1) of K-tile (g>>1): A 256x32 + B 256x32 = 32 KB,
// lives in LDS slot g&3. 4 slots = 128 KiB.
// Slot layout (per matrix part, 8192 elems): physical row p in [0,128) of
// 128 B; logical row r=(side*128+p), side=quad>>2; quad q in [0,8) stores
// (side, ke-group) XOR-swizzled: q' = quad ^ (p&7). 16-lane column reads hit
// 8 distinct quads (2-way = free).
// Pipeline: group g issued 4 ahead at the barrier that retires slot g&3;
// waits are counted (vmcnt(8) steady; 4/0 only in the last two tiles).
// ============================================================================

// stage one group (4 global_load_lds / thread): A then B, fixed issue order.
__device__ __forceinline__ void stage_group(const unsigned short* __restrict__ GA, long lda,
                                            const unsigned short* __restrict__ GB, long ldb,
                                            int kcol, unsigned short* __restrict__ Ldst,
                                            int wid, int lane) {
  const int quad = (lane & 7) ^ (lane >> 3);
  const int rr   = (quad >> 2) * 128 + wid * 16 + (lane >> 3);
  const int col  = kcol + (quad & 3) * 8;
#pragma unroll
  for (int j = 0; j < 2; ++j)
    __builtin_amdgcn_global_load_lds((g_u32*)(GA + (long)(rr + j * 8) * lda + col),
                                     (l_u32*)(Ldst + (wid * 128 + j * 64) * 8), 16, 0, 0);
#pragma unroll
  for (int j = 0; j < 2; ++j)
    __builtin_amdgcn_global_load_lds((g_u32*)(GB + (long)(rr + j * 8) * ldb + col),
                                     (l_u32*)(Ldst + 8192 + (wid * 128 + j * 64) * 8), 16, 0, 0);
}

#define DS_AV2(LA, MS)                                                        \
  _Pragma("unroll") for (int i_ = 0; i_ < 4; ++i_) {                          \
    const int p_ = (MS) * 64 + i_ * 16 + lr;                                  \
    const int q_ = (wm * 4 + lh) ^ (lr & 7);                                  \
    av[i_] = *(const frag8*)((LA) + p_ * 64 + q_ * 8);                        \
  }
#define DS_BV2(LB)                                                            \
  _Pragma("unroll") for (int n_ = 0; n_ < 4; ++n_) {                          \
    const int p_ = (wn & 1) * 64 + n_ * 16 + lr;                              \
    const int q_ = ((wn >> 1) * 4 + lh) ^ (lr & 7);                           \
    bv[n_] = *(const frag8*)((LB) + p_ * 64 + q_ * 8);                        \
  }
#define MFMA16(MS)                                                            \
  __builtin_amdgcn_s_setprio(1);                                              \
  _Pragma("unroll") for (int i_ = 0; i_ < 4; ++i_)                            \
  _Pragma("unroll") for (int n_ = 0; n_ < 4; ++n_)                            \
    acc[(MS) * 4 + i_][n_] = __builtin_amdgcn_mfma_f32_16x16x32_bf16(         \
        av[i_], bv[n_], acc[(MS) * 4 + i_][n_], 0, 0, 0);                     \
  __builtin_amdgcn_s_setprio(0);
#define LGKM0                                                                 \
  asm volatile("s_waitcnt lgkmcnt(0)" ::: "memory");                          \
  __builtin_amdgcn_sched_barrier(0)
#define BARRIER                                                               \
  __builtin_amdgcn_s_barrier();                                               \
  __builtin_amdgcn_sched_barrier(0)

// MODE: 0 = elu(v+bias[col])+1 -> bf16   (Q projection)
//       1 = elu(v+bias[row])+1 -> bf16   (K^T projection)
//       2 = v+bias[row]        -> bf16   (V^T projection)
//       3 = v+bias[col]        -> f32    (final output projection)
template <int MODE, bool XMAJOR>
__global__ __launch_bounds__(512, 2) void gemm256_nt_kernel(
    const unsigned short* __restrict__ A, long lda,
    const unsigned short* __restrict__ Bm, long ldb,
    void* __restrict__ Cv, long ldc,
    const float* __restrict__ bias, int K) {
  __shared__ unsigned short sh[65536];   // 128 KiB = 4 slots x 32 KB
  const int lane = threadIdx.x & 63, wid = threadIdx.x >> 6;
  const int wm = wid >> 2, wn = wid & 3;
  const int lr = lane & 15, lh = lane >> 4;

  // T1 bijective XCD swizzle; per-XCD chunk covers a contiguous block range.
  const int gx = gridDim.x, gy = gridDim.y;
  const int cpx = (gx * gy) >> 3;
  const int P = blockIdx.y * gx + blockIdx.x;
  const int Lw = (P & 7) * cpx + (P >> 3);
  int bx, by;
  if (XMAJOR) { bx = Lw / gy; by = Lw - bx * gy; }
  else        { by = Lw / gx; bx = Lw - by * gx; }

  const long m0 = (long)by * 256, n0 = (long)bx * 256;
  const unsigned short* Ablk = A + m0 * lda;
  const unsigned short* Bblk = Bm + n0 * ldb;
  const int NT = K >> 6;

  f32x4 acc[8][4];
#pragma unroll
  for (int m = 0; m < 8; ++m)
#pragma unroll
    for (int n = 0; n < 4; ++n) acc[m][n] = (f32x4){0.f, 0.f, 0.f, 0.f};

  // prologue: groups 0..3 (tiles 0,1)
  stage_group(Ablk, lda, Bblk, ldb, 0,  (unsigned short*)sh,         wid, lane);
  stage_group(Ablk, lda, Bblk, ldb, 32, (unsigned short*)sh + 16384, wid, lane);
  if (NT > 1) {
    stage_group(Ablk, lda, Bblk, ldb, 64, (unsigned short*)sh + 32768, wid, lane);
    stage_group(Ablk, lda, Bblk, ldb, 96, (unsigned short*)sh + 49152, wid, lane);
  }
  asm volatile("s_waitcnt vmcnt(12)" ::: "memory");   // group 0 landed
  BARRIER;

  for (int t = 0; t < NT; ++t) {
    const int sl0 = (t & 1) * 2;
    const unsigned short* lA0 = sh + sl0 * 16384;
    const unsigned short* lB0 = lA0 + 8192;
    const unsigned short* lA1 = lA0 + 16384;
    const unsigned short* lB1 = lA1 + 8192;
    frag8 av[4], bv[4];
    // ---- ph0: MS=0, kk-half 0 ----
    DS_AV2(lA0, 0); DS_BV2(lB0);
    LGKM0; MFMA16(0);
    // ---- ph1: MS=1, kk-half 0; retire slot sl0, stage group 2t+4 ----
    DS_AV2(lA0, 1);
    LGKM0;
    if (t < NT - 1) asm volatile("s_waitcnt vmcnt(8)" ::: "memory");  // G(2t+1) landed
    else            asm volatile("s_waitcnt vmcnt(0)" ::: "memory");
    BARRIER;                                   // all waves done reading slot sl0
    if (t + 2 < NT)
      stage_group(Ablk, lda, Bblk, ldb, (t + 2) * 64,
                  (unsigned short*)sh + sl0 * 16384, wid, lane);
    MFMA16(1);
    // ---- ph2: MS=0, kk-half 1 ----
    DS_AV2(lA1, 0); DS_BV2(lB1);
    LGKM0; MFMA16(0);
    // ---- ph3: MS=1, kk-half 1; retire slot sl0+1, stage group 2t+5 ----
    DS_AV2(lA1, 1);
    LGKM0;
    if (t < NT - 1) {
      if (t < NT - 2) asm volatile("s_waitcnt vmcnt(8)" ::: "memory"); // G(2t+2) landed
      else            asm volatile("s_waitcnt vmcnt(4)" ::: "memory");
      BARRIER;                                 // all waves done reading slot sl0+1
      if (t + 2 < NT)
        stage_group(Ablk, lda, Bblk, ldb, (t + 2) * 64 + 32,
                    (unsigned short*)sh + (sl0 + 1) * 16384, wid, lane);
    }
    MFMA16(1);
  }

  // epilogue: frag m covers rows (m>>2)*64 + (m&3)*16 of the wave's 128
#pragma unroll
  for (int m = 0; m < 8; ++m)
#pragma unroll
    for (int n = 0; n < 4; ++n)
#pragma unroll
      for (int r = 0; r < 4; ++r) {
        long row = m0 + wm * 128 + (m >> 2) * 64 + (m & 3) * 16 + lh * 4 + r;
        long col = n0 + wn * 64 + n * 16 + lr;
        float v = acc[m][n][r];
        if (MODE == 0) {
          v += bias[col]; v = v > 0.f ? v + 1.f : __expf(v);
          ((unsigned short*)Cv)[row * ldc + col] = f2bf(v);
        } else if (MODE == 1) {
          v += bias[row]; v = v > 0.f ? v + 1.f : __expf(v);
          ((unsigned short*)Cv)[row * ldc + col] = f2bf(v);
        } else if (MODE == 2) {
          v += bias[row];
          ((unsigned short*)Cv)[row * ldc + col] = f2bf(v);
        } else {
          v += bias[col];
          ((float*)Cv)[row * ldc + col] = v;
        }
      }
}

// ============================================================================
// 128x128 path (attention core) — unchanged.
// ============================================================================
__device__ __forceinline__ void stage_tile(const unsigned short* __restrict__ G,
                                           long ld, unsigned short* __restrict__ L) {
  const int w = threadIdx.x >> 6, l = threadIdx.x & 63;
#pragma unroll
  for (int r = 0; r < 4; ++r) {
    const int chunk = w * 4 + r;
    const int row = chunk * 8 + (l >> 3);
    const int col = (l & 7) * 8;
    __builtin_amdgcn_global_load_lds((g_u32*)(G + (long)row * ld + col),
                                     (l_u32*)(L + chunk * 512), 16, 0, 0);
  }
}

__device__ __forceinline__ void gemm_mainloop(const unsigned short* __restrict__ A, long lda,
                                              const unsigned short* __restrict__ B, long ldb,
                                              int K, unsigned short* lA, unsigned short* lB,
                                              f32x4 acc[4][4]) {
  const int lane = threadIdx.x & 63;
  const int wid  = threadIdx.x >> 6;
  const int wr = wid >> 1, wc = wid & 1;
  const int lr = lane & 15, lh = lane >> 4;
  for (int k0 = 0; k0 < K; k0 += 64) {
    stage_tile(A + k0, lda, lA);
    stage_tile(B + k0, ldb, lB);
    __syncthreads();
#pragma unroll
    for (int kk = 0; kk < 64; kk += 32) {
      frag8 av[4], bv[4];
#pragma unroll
      for (int m = 0; m < 4; ++m)
        av[m] = *reinterpret_cast<const frag8*>(lA + (wr * 64 + m * 16 + lr) * 64 + kk + lh * 8);
#pragma unroll
      for (int n = 0; n < 4; ++n)
        bv[n] = *reinterpret_cast<const frag8*>(lB + (wc * 64 + n * 16 + lr) * 64 + kk + lh * 8);
#pragma unroll
      for (int m = 0; m < 4; ++m)
#pragma unroll
        for (int n = 0; n < 4; ++n)
          acc[m][n] = __builtin_amdgcn_mfma_f32_16x16x32_bf16(av[m], bv[n], acc[m][n], 0, 0, 0);
    }
    __syncthreads();
  }
}

#define ACC_INIT(acc)                                   \
  _Pragma("unroll") for (int m_ = 0; m_ < 4; ++m_)      \
  _Pragma("unroll") for (int n_ = 0; n_ < 4; ++n_)      \
      acc[m_][n_] = (f32x4){0.f, 0.f, 0.f, 0.f};

// ---- KV^T partials: per (bh, chunk) C[e,d] = sum_t V[t,e]K[t,d] over 512 t --
__global__ __launch_bounds__(256) void kvt_partial_kernel(
    const unsigned short* __restrict__ VT, const unsigned short* __restrict__ KT,
    float* __restrict__ part) {
  __shared__ unsigned short lA[128 * 64], lB[128 * 64];
  const int z = blockIdx.x;            // 0..511 = bh*8 + chunk
  const int bh = z >> 3, c = z & 7;
  const int b = bh >> 4, h = bh & 15;
  const long tOff = (long)b * SEQ + (long)c * 512;
  const unsigned short* A  = VT + (long)(h * DKH) * M_TOK + tOff;
  const unsigned short* Bm = KT + (long)(h * DKH) * M_TOK + tOff;
  f32x4 acc[4][4];
  ACC_INIT(acc);
  gemm_mainloop(A, M_TOK, Bm, M_TOK, 512, lA, lB, acc);
  const int lane = threadIdx.x & 63, wid = threadIdx.x >> 6;
  const int wr = wid >> 1, wc = wid & 1, lr = lane & 15, lh = lane >> 4;
  float* out = part + (long)z * (DKH * DKH);
#pragma unroll
  for (int m = 0; m < 4; ++m)
#pragma unroll
    for (int n = 0; n < 4; ++n)
#pragma unroll
      for (int r = 0; r < 4; ++r) {
        int row = wr * 64 + m * 16 + lh * 4 + r;   // e
        int col = wc * 64 + n * 16 + lr;           // d
        out[row * DKH + col] = acc[m][n][r];
      }
}

__global__ __launch_bounds__(256) void reduce_kvt_kernel(
    const float* __restrict__ part, unsigned short* __restrict__ kvt) {
  int i = blockIdx.x * 256 + threadIdx.x;          // over 64*16384
  if (i < NBH * DKH * DKH) {
    int bh = i >> 14, j = i & 16383;
    float s = 0.f;
#pragma unroll
    for (int c = 0; c < 8; ++c) s += part[(((long)bh * 8 + c) << 14) + j];
    kvt[i] = f2bf(s);
  }
}

// ---- K row sums ------------------------------------------------------------
__global__ __launch_bounds__(256) void ksum_kernel(const unsigned short* __restrict__ KT,
                                                   float* __restrict__ ksum) {
  int gr = blockIdx.x * 4 + (threadIdx.x >> 6);    // 0..8191 = bh*128+d
  int lane = threadIdx.x & 63;
  int bh = gr >> 7, d = gr & 127;
  int b = bh >> 4, h = bh & 15;
  const unsigned short* p = KT + (long)(h * DKH + d) * M_TOK + (long)b * SEQ;
  float s = 0.f;
#pragma unroll
  for (int i = 0; i < 8; ++i) {
    uint4 v = *reinterpret_cast<const uint4*>(p + (i * 64 + lane) * 8);
    unsigned w[4] = {v.x, v.y, v.z, v.w};
#pragma unroll
    for (int j = 0; j < 4; ++j) {
      s += bf2f((unsigned short)(w[j] & 0xffff));
      s += bf2f((unsigned short)(w[j] >> 16));
    }
  }
#pragma unroll
  for (int o = 32; o > 0; o >>= 1) s += __shfl_down(s, o);
  if (lane == 0) ksum[gr] = s;
}

// ---- qsum ------------------------------------------------------------------
__global__ __launch_bounds__(256) void qsum_kernel(const unsigned short* __restrict__ Q,
                                                   const float* __restrict__ ksum,
                                                   float* __restrict__ qsum) {
  int gr = blockIdx.x * 4 + (threadIdx.x >> 6);    // 0..262143 = bh*4096 + s
  int lane = threadIdx.x & 63;
  int bh = gr >> 12, s = gr & 4095;
  int b = bh >> 4, h = bh & 15;
  const unsigned short* q = Q + ((long)b * SEQ + s) * D_MODEL + h * DKH + lane * 2;
  unsigned u = *reinterpret_cast<const unsigned*>(q);
  const float* ks = ksum + bh * DKH + lane * 2;
  float sum = bf2f((unsigned short)(u & 0xffff)) * ks[0] +
              bf2f((unsigned short)(u >> 16)) * ks[1];
#pragma unroll
  for (int o = 32; o > 0; o >>= 1) sum += __shfl_down(sum, o);
  if (lane == 0) qsum[gr] = sum;
}

// ---- QKV -------------------------------------------------------------------
__global__ __launch_bounds__(256) void qkv_kernel(const unsigned short* __restrict__ Q,
                                                  const unsigned short* __restrict__ KVT,
                                                  const float* __restrict__ qsum,
                                                  unsigned short* __restrict__ attn) {
  __shared__ unsigned short lA[128 * 64], lB[128 * 64];
  const int z = blockIdx.z, b = z >> 4, h = z & 15;
  const long m0 = (long)blockIdx.y * 128;
  const unsigned short* A  = Q + ((long)b * SEQ + m0) * D_MODEL + h * DKH;
  const unsigned short* Bm = KVT + (long)z * (DKH * DKH);
  f32x4 acc[4][4];
  ACC_INIT(acc);
  gemm_mainloop(A, D_MODEL, Bm, DKH, DKH, lA, lB, acc);
  const int lane = threadIdx.x & 63, wid = threadIdx.x >> 6;
  const int wr = wid >> 1, wc = wid & 1, lr = lane & 15, lh = lane >> 4;
#pragma unroll
  for (int m = 0; m < 4; ++m)
#pragma unroll
    for (int n = 0; n < 4; ++n)
#pragma unroll
      for (int r = 0; r < 4; ++r) {
        long row = m0 + wr * 64 + m * 16 + lh * 4 + r;   // s in [0,4096)
        int  col = wc * 64 + n * 16 + lr;                // e in [0,128)
        float dnm = qsum[(long)z * SEQ + row] + 1e-8f;
        float v = acc[m][n][r] / dnm;
        attn[((long)b * SEQ + row) * D_MODEL + h * DKH + col] = f2bf(v);
      }
}

// ---- workspace layout (bytes) ----------------------------------------------
#define OFF_XB   0L
#define OFF_WQ   (OFF_XB + (long)M_TOK * D_MODEL * 2)
#define OFF_WK   (OFF_WQ + (long)D_MODEL * D_MODEL * 2)
#define OFF_WV   (OFF_WK + (long)D_MODEL * D_MODEL * 2)
#define OFF_WO   (OFF_WV + (long)D_MODEL * D_MODEL * 2)
#define OFF_QB   (OFF_WO + (long)D_MODEL * D_MODEL * 2)
#define OFF_KT   (OFF_QB + (long)M_TOK * D_MODEL * 2)
#define OFF_VT   (OFF_KT + (long)M_TOK * D_MODEL * 2)
#define OFF_PART (OFF_VT + (long)M_TOK * D_MODEL * 2)
#define OFF_KVT  (OFF_PART + (long)512 * DKH * DKH * 4)
#define OFF_KSUM (OFF_KVT + (long)NBH * DKH * DKH * 2)
#define OFF_QSUM (OFF_KSUM + (long)NBH * DKH * 4)
#define OFF_ATTN OFF_XB   // alias: x_bf16 dead after V^T projection

extern "C" void kernel_launch(void* const* d_in, const int* in_sizes, int n_in,
                              void* d_out, int out_size, void* d_ws, size_t ws_size,
                              hipStream_t stream) {
  const float* x  = (const float*)d_in[0];
  const float* wq = (const float*)d_in[1];
  const float* bq = (const float*)d_in[2];
  const float* wk = (const float*)d_in[3];
  const float* bk = (const float*)d_in[4];
  const float* wv = (const float*)d_in[5];
  const float* bv = (const float*)d_in[6];
  const float* wo = (const float*)d_in[7];
  const float* bo = (const float*)d_in[8];

  char* ws = (char*)d_ws;
  unsigned short* xb   = (unsigned short*)(ws + OFF_XB);
  unsigned short* wqb  = (unsigned short*)(ws + OFF_WQ);
  unsigned short* wkb  = (unsigned short*)(ws + OFF_WK);
  unsigned short* wvb  = (unsigned short*)(ws + OFF_WV);
  unsigned short* wob  = (unsigned short*)(ws + OFF_WO);
  unsigned short* Qb   = (unsigned short*)(ws + OFF_QB);
  unsigned short* KTb  = (unsigned short*)(ws + OFF_KT);
  unsigned short* VTb  = (unsigned short*)(ws + OFF_VT);
  float*          part = (float*)(ws + OFF_PART);
  unsigned short* KVTb = (unsigned short*)(ws + OFF_KVT);
  float*          ksum = (float*)(ws + OFF_KSUM);
  float*          qsum = (float*)(ws + OFF_QSUM);
  unsigned short* attn = (unsigned short*)(ws + OFF_ATTN);

  dim3 blk(256);
  dim3 blk5(512);

  // fp32 -> bf16
  convert_f2bf_kernel<<<(M_TOK * D_MODEL / 4) / 256, blk, 0, stream>>>(x, xb, M_TOK * D_MODEL / 4);
  convert_f2bf_kernel<<<(D_MODEL * D_MODEL / 4) / 256, blk, 0, stream>>>(wq, wqb, D_MODEL * D_MODEL / 4);
  convert_f2bf_kernel<<<(D_MODEL * D_MODEL / 4) / 256, blk, 0, stream>>>(wk, wkb, D_MODEL * D_MODEL / 4);
  convert_f2bf_kernel<<<(D_MODEL * D_MODEL / 4) / 256, blk, 0, stream>>>(wv, wvb, D_MODEL * D_MODEL / 4);
  convert_f2bf_kernel<<<(D_MODEL * D_MODEL / 4) / 256, blk, 0, stream>>>(wo, wob, D_MODEL * D_MODEL / 4);

  // Q = elu(x@Wq^T + bq)+1                       (M_TOK x 2048)
  gemm256_nt_kernel<0, false><<<dim3(D_MODEL / 256, M_TOK / 256), blk5, 0, stream>>>(
      xb, D_MODEL, wqb, D_MODEL, Qb, D_MODEL, bq, D_MODEL);
  // K^T = elu(Wk@x^T + bk)+1  (2048 x M_TOK), V^T = Wv@x^T + bv
  gemm256_nt_kernel<1, true><<<dim3(M_TOK / 256, D_MODEL / 256), blk5, 0, stream>>>(
      wkb, D_MODEL, xb, D_MODEL, KTb, M_TOK, bk, D_MODEL);
  gemm256_nt_kernel<2, true><<<dim3(M_TOK / 256, D_MODEL / 256), blk5, 0, stream>>>(
      wvb, D_MODEL, xb, D_MODEL, VTb, M_TOK, bv, D_MODEL);

  // KV^T per (b,h) via split-K partials + reduce
  kvt_partial_kernel<<<512, blk, 0, stream>>>(VTb, KTb, part);
  reduce_kvt_kernel<<<(NBH * DKH * DKH) / 256, blk, 0, stream>>>(part, KVTb);

  // K_sum and per-row denominators
  ksum_kernel<<<(NBH * DKH) / 4, blk, 0, stream>>>(KTb, ksum);
  qsum_kernel<<<(NBH * SEQ) / 4, blk, 0, stream>>>(Qb, ksum, qsum);

  // attn = (Q @ KV) / (Q . Ksum + 1e-8)   -> bf16 (aliases xb)
  qkv_kernel<<<dim3(1, SEQ / 128, NBH), blk, 0, stream>>>(Qb, KVTb, qsum, attn);

  // out = attn @ Wo^T + bo  -> fp32
  gemm256_nt_kernel<3, false><<<dim3(D_MODEL / 256, M_TOK / 256), blk5, 0, stream>>>(
      attn, D_MODEL, wob, D_MODEL, d_out, D_MODEL, bo, D_MODEL);
}

// Round 6
// 694.427 us; speedup vs baseline: 1.0101x; 1.0101x over previous
//
#include <hip/hip_runtime.h>

// Linear attention (elu+1 feature map), B=4 S=4096 D=2048 H=16 dk=128.
// bf16 MFMA, fp32 accumulate.
// Round 6: register-double-buffered phase pipeline — ds_reads for phase p+1
// issued before MFMA of phase p; compiler-managed counted lgkm waits (no
// forced lgkm drains inside phases, no sched_barrier pins); counted vmcnt(8)
// staging pipeline; lgkmcnt(0) only at slot-retire barriers (free: covers
// 4 reads issued a full phase earlier; required before slot overwrite).

#define D_MODEL 2048
#define SEQ     4096
#define BATCH   4
#define HEADS   16
#define DKH     128
#define M_TOK   16384   // BATCH*SEQ
#define NBH     64      // BATCH*HEADS

using frag8 = __attribute__((ext_vector_type(8))) short;   // 8 bf16 (4 VGPRs)
using f32x4 = __attribute__((ext_vector_type(4))) float;   // 4 fp32 acc

typedef __attribute__((address_space(1))) const unsigned int g_u32;
typedef __attribute__((address_space(3))) unsigned int       l_u32;

__device__ __forceinline__ unsigned short f2bf(float f) {
  unsigned u = __float_as_uint(f);
  u = u + 0x7fffu + ((u >> 16) & 1u);   // round-to-nearest-even
  return (unsigned short)(u >> 16);
}
__device__ __forceinline__ float bf2f(unsigned short h) {
  return __uint_as_float(((unsigned)h) << 16);
}

// ---- fp32 -> bf16 convert (vectorized) --------------------------------------
__global__ __launch_bounds__(256) void convert_f2bf_kernel(
    const float* __restrict__ in, unsigned short* __restrict__ out, int n4) {
  int i = blockIdx.x * 256 + threadIdx.x;
  if (i < n4) {
    float4 v = reinterpret_cast<const float4*>(in)[i];
    ushort4 o;
    o.x = f2bf(v.x); o.y = f2bf(v.y); o.z = f2bf(v.z); o.w = f2bf(v.w);
    reinterpret_cast<ushort4*>(out)[i] = o;
  }
}

// ============================================================================
// 256x256x(BK=64) group-pipelined GEMM, C = A(256xK)*B(256xK)^T, bf16 NT.
// 512 thr = 8 waves (2M x 4N); per-wave C = 128x64 = (2 MS-halves x 4m) x 4n.
// Group g = kk-half (g&1) of K-tile (g>>1): A 256x32 + B 256x32 = 32 KB,
// lives in LDS slot g&3; 4 slots = 128 KiB. Slot layout: phys row p in
// [0,128) x 8 quads of 16B; logical row r = (q>>2)*128+p, swizzle q'=q^(p&7).
// Pipeline: group issued 4 ahead at slot-retire barriers; vmcnt(8) steady;
// frag reads issued one phase ahead into ping-pong register sets.
// ============================================================================

__device__ __forceinline__ void stage_group(const unsigned short* __restrict__ GA, long lda,
                                            const unsigned short* __restrict__ GB, long ldb,
                                            int kcol, unsigned short* __restrict__ Ldst,
                                            int wid, int lane) {
  const int quad = (lane & 7) ^ (lane >> 3);
  const int rr   = (quad >> 2) * 128 + wid * 16 + (lane >> 3);
  const int col  = kcol + (quad & 3) * 8;
#pragma unroll
  for (int j = 0; j < 2; ++j)
    __builtin_amdgcn_global_load_lds((g_u32*)(GA + (long)(rr + j * 8) * lda + col),
                                     (l_u32*)(Ldst + (wid * 128 + j * 64) * 8), 16, 0, 0);
#pragma unroll
  for (int j = 0; j < 2; ++j)
    __builtin_amdgcn_global_load_lds((g_u32*)(GB + (long)(rr + j * 8) * ldb + col),
                                     (l_u32*)(Ldst + 8192 + (wid * 128 + j * 64) * 8), 16, 0, 0);
}

#define DS_AV_TO(dst, LA, MS)                                                 \
  _Pragma("unroll") for (int i_ = 0; i_ < 4; ++i_) {                          \
    const int p_ = (MS) * 64 + i_ * 16 + lr;                                  \
    const int q_ = (wm * 4 + lh) ^ (lr & 7);                                  \
    dst[i_] = *(const frag8*)((LA) + p_ * 64 + q_ * 8);                       \
  }
#define DS_BV_TO(dst, LB)                                                     \
  _Pragma("unroll") for (int n_ = 0; n_ < 4; ++n_) {                          \
    const int p_ = (wn & 1) * 64 + n_ * 16 + lr;                              \
    const int q_ = ((wn >> 1) * 4 + lh) ^ (lr & 7);                           \
    dst[n_] = *(const frag8*)((LB) + p_ * 64 + q_ * 8);                       \
  }
#define MFMA16_AB(a_, b_, MS)                                                 \
  __builtin_amdgcn_s_setprio(1);                                              \
  _Pragma("unroll") for (int i_ = 0; i_ < 4; ++i_)                            \
  _Pragma("unroll") for (int n_ = 0; n_ < 4; ++n_)                            \
    acc[(MS) * 4 + i_][n_] = __builtin_amdgcn_mfma_f32_16x16x32_bf16(         \
        a_[i_], b_[n_], acc[(MS) * 4 + i_][n_], 0, 0, 0);                     \
  __builtin_amdgcn_s_setprio(0);

// MODE: 0 = elu(v+bias[col])+1 -> bf16   (Q projection)
//       1 = elu(v+bias[row])+1 -> bf16   (K^T projection)
//       2 = v+bias[row]        -> bf16   (V^T projection)
//       3 = v+bias[col]        -> f32    (final output projection)
template <int MODE, bool XMAJOR>
__global__ __launch_bounds__(512, 2) void gemm256_nt_kernel(
    const unsigned short* __restrict__ A, long lda,
    const unsigned short* __restrict__ Bm, long ldb,
    void* __restrict__ Cv, long ldc,
    const float* __restrict__ bias, int K) {
  __shared__ unsigned short sh[65536];   // 128 KiB = 4 slots x 32 KB
  const int lane = threadIdx.x & 63, wid = threadIdx.x >> 6;
  const int wm = wid >> 2, wn = wid & 3;
  const int lr = lane & 15, lh = lane >> 4;

  // T1 bijective XCD swizzle
  const int gx = gridDim.x, gy = gridDim.y;
  const int cpx = (gx * gy) >> 3;
  const int P = blockIdx.y * gx + blockIdx.x;
  const int Lw = (P & 7) * cpx + (P >> 3);
  int bx, by;
  if (XMAJOR) { bx = Lw / gy; by = Lw - bx * gy; }
  else        { by = Lw / gx; bx = Lw - by * gx; }

  const long m0 = (long)by * 256, n0 = (long)bx * 256;
  const unsigned short* Ablk = A + m0 * lda;
  const unsigned short* Bblk = Bm + n0 * ldb;
  const int NT = K >> 6;

  f32x4 acc[8][4];
#pragma unroll
  for (int m = 0; m < 8; ++m)
#pragma unroll
    for (int n = 0; n < 4; ++n) acc[m][n] = (f32x4){0.f, 0.f, 0.f, 0.f};

  // prologue: groups 0..3 (tiles 0,1)
  stage_group(Ablk, lda, Bblk, ldb, 0,  (unsigned short*)sh,         wid, lane);
  stage_group(Ablk, lda, Bblk, ldb, 32, (unsigned short*)sh + 16384, wid, lane);
  if (NT > 1) {
    stage_group(Ablk, lda, Bblk, ldb, 64, (unsigned short*)sh + 32768, wid, lane);
    stage_group(Ablk, lda, Bblk, ldb, 96, (unsigned short*)sh + 49152, wid, lane);
  }
  asm volatile("s_waitcnt vmcnt(12)" ::: "memory");   // group 0 landed
  __builtin_amdgcn_s_barrier();

  frag8 avc[4], avn[4], bvc[4], bvn[4];
  DS_AV_TO(avc, (const unsigned short*)sh, 0);
  DS_BV_TO(bvc, (const unsigned short*)sh + 8192);

  for (int t = 0; t < NT; ++t) {
    const unsigned short* sl0 = (const unsigned short*)sh + ((t & 1) * 2) * 16384;
    const unsigned short* sl1 = sl0 + 16384;
    const unsigned short* nsl = (const unsigned short*)sh + (((t + 1) & 1) * 2) * 16384;
    // ---- ph0: issue (MS1,k0) reads, MFMA (MS0,k0) ----
    DS_AV_TO(avn, sl0, 1);
    MFMA16_AB(avc, bvc, 0);
    // ---- ph1: retire slot sl0; stage group 2t+4; issue (MS0,k1)+B(k1) ----
    asm volatile("s_waitcnt lgkmcnt(0)" ::: "memory");   // avn reads of sl0 done
    if (t < NT - 1) asm volatile("s_waitcnt vmcnt(8)" ::: "memory");  // G(2t+1) landed
    else            asm volatile("s_waitcnt vmcnt(0)" ::: "memory");
    __builtin_amdgcn_s_barrier();
    if (t + 2 < NT)
      stage_group(Ablk, lda, Bblk, ldb, (t + 2) * 64,
                  (unsigned short*)sl0, wid, lane);
    DS_AV_TO(avc, sl1, 0);
    DS_BV_TO(bvn, sl1 + 8192);
    MFMA16_AB(avn, bvc, 1);
    // ---- ph2: issue (MS1,k1), MFMA (MS0,k1) ----
    DS_AV_TO(avn, sl1, 1);
    MFMA16_AB(avc, bvn, 0);
    // ---- ph3: retire slot sl1; stage group 2t+5; issue next tile (MS0,k0') ----
    asm volatile("s_waitcnt lgkmcnt(0)" ::: "memory");   // avn reads of sl1 done
    if (t < NT - 2)       asm volatile("s_waitcnt vmcnt(8)" ::: "memory"); // G(2t+2) landed
    else if (t == NT - 2) asm volatile("s_waitcnt vmcnt(4)" ::: "memory");
    if (t < NT - 1) {
      __builtin_amdgcn_s_barrier();
      if (t + 2 < NT)
        stage_group(Ablk, lda, Bblk, ldb, (t + 2) * 64 + 32,
                    (unsigned short*)sl1, wid, lane);
      DS_AV_TO(avc, nsl, 0);
      DS_BV_TO(bvc, nsl + 8192);
    }
    MFMA16_AB(avn, bvn, 1);
  }

  // epilogue: frag m covers rows (m>>2)*64 + (m&3)*16 of the wave's 128
#pragma unroll
  for (int m = 0; m < 8; ++m)
#pragma unroll
    for (int n = 0; n < 4; ++n)
#pragma unroll
      for (int r = 0; r < 4; ++r) {
        long row = m0 + wm * 128 + (m >> 2) * 64 + (m & 3) * 16 + lh * 4 + r;
        long col = n0 + wn * 64 + n * 16 + lr;
        float v = acc[m][n][r];
        if (MODE == 0) {
          v += bias[col]; v = v > 0.f ? v + 1.f : __expf(v);
          ((unsigned short*)Cv)[row * ldc + col] = f2bf(v);
        } else if (MODE == 1) {
          v += bias[row]; v = v > 0.f ? v + 1.f : __expf(v);
          ((unsigned short*)Cv)[row * ldc + col] = f2bf(v);
        } else if (MODE == 2) {
          v += bias[row];
          ((unsigned short*)Cv)[row * ldc + col] = f2bf(v);
        } else {
          v += bias[col];
          ((float*)Cv)[row * ldc + col] = v;
        }
      }
}

// ============================================================================
// 128x128 path (attention core) — unchanged.
// ============================================================================
__device__ __forceinline__ void stage_tile(const unsigned short* __restrict__ G,
                                           long ld, unsigned short* __restrict__ L) {
  const int w = threadIdx.x >> 6, l = threadIdx.x & 63;
#pragma unroll
  for (int r = 0; r < 4; ++r) {
    const int chunk = w * 4 + r;
    const int row = chunk * 8 + (l >> 3);
    const int col = (l & 7) * 8;
    __builtin_amdgcn_global_load_lds((g_u32*)(G + (long)row * ld + col),
                                     (l_u32*)(L + chunk * 512), 16, 0, 0);
  }
}

__device__ __forceinline__ void gemm_mainloop(const unsigned short* __restrict__ A, long lda,
                                              const unsigned short* __restrict__ B, long ldb,
                                              int K, unsigned short* lA, unsigned short* lB,
                                              f32x4 acc[4][4]) {
  const int lane = threadIdx.x & 63;
  const int wid  = threadIdx.x >> 6;
  const int wr = wid >> 1, wc = wid & 1;
  const int lr = lane & 15, lh = lane >> 4;
  for (int k0 = 0; k0 < K; k0 += 64) {
    stage_tile(A + k0, lda, lA);
    stage_tile(B + k0, ldb, lB);
    __syncthreads();
#pragma unroll
    for (int kk = 0; kk < 64; kk += 32) {
      frag8 av[4], bv[4];
#pragma unroll
      for (int m = 0; m < 4; ++m)
        av[m] = *reinterpret_cast<const frag8*>(lA + (wr * 64 + m * 16 + lr) * 64 + kk + lh * 8);
#pragma unroll
      for (int n = 0; n < 4; ++n)
        bv[n] = *reinterpret_cast<const frag8*>(lB + (wc * 64 + n * 16 + lr) * 64 + kk + lh * 8);
#pragma unroll
      for (int m = 0; m < 4; ++m)
#pragma unroll
        for (int n = 0; n < 4; ++n)
          acc[m][n] = __builtin_amdgcn_mfma_f32_16x16x32_bf16(av[m], bv[n], acc[m][n], 0, 0, 0);
    }
    __syncthreads();
  }
}

#define ACC_INIT(acc)                                   \
  _Pragma("unroll") for (int m_ = 0; m_ < 4; ++m_)      \
  _Pragma("unroll") for (int n_ = 0; n_ < 4; ++n_)      \
      acc[m_][n_] = (f32x4){0.f, 0.f, 0.f, 0.f};

// ---- KV^T partials: per (bh, chunk) C[e,d] = sum_t V[t,e]K[t,d] over 512 t --
__global__ __launch_bounds__(256) void kvt_partial_kernel(
    const unsigned short* __restrict__ VT, const unsigned short* __restrict__ KT,
    float* __restrict__ part) {
  __shared__ unsigned short lA[128 * 64], lB[128 * 64];
  const int z = blockIdx.x;            // 0..511 = bh*8 + chunk
  const int bh = z >> 3, c = z & 7;
  const int b = bh >> 4, h = bh & 15;
  const long tOff = (long)b * SEQ + (long)c * 512;
  const unsigned short* A  = VT + (long)(h * DKH) * M_TOK + tOff;
  const unsigned short* Bm = KT + (long)(h * DKH) * M_TOK + tOff;
  f32x4 acc[4][4];
  ACC_INIT(acc);
  gemm_mainloop(A, M_TOK, Bm, M_TOK, 512, lA, lB, acc);
  const int lane = threadIdx.x & 63, wid = threadIdx.x >> 6;
  const int wr = wid >> 1, wc = wid & 1, lr = lane & 15, lh = lane >> 4;
  float* out = part + (long)z * (DKH * DKH);
#pragma unroll
  for (int m = 0; m < 4; ++m)
#pragma unroll
    for (int n = 0; n < 4; ++n)
#pragma unroll
      for (int r = 0; r < 4; ++r) {
        int row = wr * 64 + m * 16 + lh * 4 + r;   // e
        int col = wc * 64 + n * 16 + lr;           // d
        out[row * DKH + col] = acc[m][n][r];
      }
}

__global__ __launch_bounds__(256) void reduce_kvt_kernel(
    const float* __restrict__ part, unsigned short* __restrict__ kvt) {
  int i = blockIdx.x * 256 + threadIdx.x;          // over 64*16384
  if (i < NBH * DKH * DKH) {
    int bh = i >> 14, j = i & 16383;
    float s = 0.f;
#pragma unroll
    for (int c = 0; c < 8; ++c) s += part[(((long)bh * 8 + c) << 14) + j];
    kvt[i] = f2bf(s);
  }
}

// ---- K row sums ------------------------------------------------------------
__global__ __launch_bounds__(256) void ksum_kernel(const unsigned short* __restrict__ KT,
                                                   float* __restrict__ ksum) {
  int gr = blockIdx.x * 4 + (threadIdx.x >> 6);    // 0..8191 = bh*128+d
  int lane = threadIdx.x & 63;
  int bh = gr >> 7, d = gr & 127;
  int b = bh >> 4, h = bh & 15;
  const unsigned short* p = KT + (long)(h * DKH + d) * M_TOK + (long)b * SEQ;
  float s = 0.f;
#pragma unroll
  for (int i = 0; i < 8; ++i) {
    uint4 v = *reinterpret_cast<const uint4*>(p + (i * 64 + lane) * 8);
    unsigned w[4] = {v.x, v.y, v.z, v.w};
#pragma unroll
    for (int j = 0; j < 4; ++j) {
      s += bf2f((unsigned short)(w[j] & 0xffff));
      s += bf2f((unsigned short)(w[j] >> 16));
    }
  }
#pragma unroll
  for (int o = 32; o > 0; o >>= 1) s += __shfl_down(s, o);
  if (lane == 0) ksum[gr] = s;
}

// ---- qsum ------------------------------------------------------------------
__global__ __launch_bounds__(256) void qsum_kernel(const unsigned short* __restrict__ Q,
                                                   const float* __restrict__ ksum,
                                                   float* __restrict__ qsum) {
  int gr = blockIdx.x * 4 + (threadIdx.x >> 6);    // 0..262143 = bh*4096 + s
  int lane = threadIdx.x & 63;
  int bh = gr >> 12, s = gr & 4095;
  int b = bh >> 4, h = bh & 15;
  const unsigned short* q = Q + ((long)b * SEQ + s) * D_MODEL + h * DKH + lane * 2;
  unsigned u = *reinterpret_cast<const unsigned*>(q);
  const float* ks = ksum + bh * DKH + lane * 2;
  float sum = bf2f((unsigned short)(u & 0xffff)) * ks[0] +
              bf2f((unsigned short)(u >> 16)) * ks[1];
#pragma unroll
  for (int o = 32; o > 0; o >>= 1) sum += __shfl_down(sum, o);
  if (lane == 0) qsum[gr] = sum;
}

// ---- QKV -------------------------------------------------------------------
__global__ __launch_bounds__(256) void qkv_kernel(const unsigned short* __restrict__ Q,
                                                  const unsigned short* __restrict__ KVT,
                                                  const float* __restrict__ qsum,
                                                  unsigned short* __restrict__ attn) {
  __shared__ unsigned short lA[128 * 64], lB[128 * 64];
  const int z = blockIdx.z, b = z >> 4, h = z & 15;
  const long m0 = (long)blockIdx.y * 128;
  const unsigned short* A  = Q + ((long)b * SEQ + m0) * D_MODEL + h * DKH;
  const unsigned short* Bm = KVT + (long)z * (DKH * DKH);
  f32x4 acc[4][4];
  ACC_INIT(acc);
  gemm_mainloop(A, D_MODEL, Bm, DKH, DKH, lA, lB, acc);
  const int lane = threadIdx.x & 63, wid = threadIdx.x >> 6;
  const int wr = wid >> 1, wc = wid & 1, lr = lane & 15, lh = lane >> 4;
#pragma unroll
  for (int m = 0; m < 4; ++m)
#pragma unroll
    for (int n = 0; n < 4; ++n)
#pragma unroll
      for (int r = 0; r < 4; ++r) {
        long row = m0 + wr * 64 + m * 16 + lh * 4 + r;   // s in [0,4096)
        int  col = wc * 64 + n * 16 + lr;                // e in [0,128)
        float dnm = qsum[(long)z * SEQ + row] + 1e-8f;
        float v = acc[m][n][r] / dnm;
        attn[((long)b * SEQ + row) * D_MODEL + h * DKH + col] = f2bf(v);
      }
}

// ---- workspace layout (bytes) ----------------------------------------------
#define OFF_XB   0L
#define OFF_WQ   (OFF_XB + (long)M_TOK * D_MODEL * 2)
#define OFF_WK   (OFF_WQ + (long)D_MODEL * D_MODEL * 2)
#define OFF_WV   (OFF_WK + (long)D_MODEL * D_MODEL * 2)
#define OFF_WO   (OFF_WV + (long)D_MODEL * D_MODEL * 2)
#define OFF_QB   (OFF_WO + (long)D_MODEL * D_MODEL * 2)
#define OFF_KT   (OFF_QB + (long)M_TOK * D_MODEL * 2)
#define OFF_VT   (OFF_KT + (long)M_TOK * D_MODEL * 2)
#define OFF_PART (OFF_VT + (long)M_TOK * D_MODEL * 2)
#define OFF_KVT  (OFF_PART + (long)512 * DKH * DKH * 4)
#define OFF_KSUM (OFF_KVT + (long)NBH * DKH * DKH * 2)
#define OFF_QSUM (OFF_KSUM + (long)NBH * DKH * 4)
#define OFF_ATTN OFF_XB   // alias: x_bf16 dead after V^T projection

extern "C" void kernel_launch(void* const* d_in, const int* in_sizes, int n_in,
                              void* d_out, int out_size, void* d_ws, size_t ws_size,
                              hipStream_t stream) {
  const float* x  = (const float*)d_in[0];
  const float* wq = (const float*)d_in[1];
  const float* bq = (const float*)d_in[2];
  const float* wk = (const float*)d_in[3];
  const float* bk = (const float*)d_in[4];
  const float* wv = (const float*)d_in[5];
  const float* bv = (const float*)d_in[6];
  const float* wo = (const float*)d_in[7];
  const float* bo = (const float*)d_in[8];

  char* ws = (char*)d_ws;
  unsigned short* xb   = (unsigned short*)(ws + OFF_XB);
  unsigned short* wqb  = (unsigned short*)(ws + OFF_WQ);
  unsigned short* wkb  = (unsigned short*)(ws + OFF_WK);
  unsigned short* wvb  = (unsigned short*)(ws + OFF_WV);
  unsigned short* wob  = (unsigned short*)(ws + OFF_WO);
  unsigned short* Qb   = (unsigned short*)(ws + OFF_QB);
  unsigned short* KTb  = (unsigned short*)(ws + OFF_KT);
  unsigned short* VTb  = (unsigned short*)(ws + OFF_VT);
  float*          part = (float*)(ws + OFF_PART);
  unsigned short* KVTb = (unsigned short*)(ws + OFF_KVT);
  float*          ksum = (float*)(ws + OFF_KSUM);
  float*          qsum = (float*)(ws + OFF_QSUM);
  unsigned short* attn = (unsigned short*)(ws + OFF_ATTN);

  dim3 blk(256);
  dim3 blk5(512);

  // fp32 -> bf16
  convert_f2bf_kernel<<<(M_TOK * D_MODEL / 4) / 256, blk, 0, stream>>>(x, xb, M_TOK * D_MODEL / 4);
  convert_f2bf_kernel<<<(D_MODEL * D_MODEL / 4) / 256, blk, 0, stream>>>(wq, wqb, D_MODEL * D_MODEL / 4);
  convert_f2bf_kernel<<<(D_MODEL * D_MODEL / 4) / 256, blk, 0, stream>>>(wk, wkb, D_MODEL * D_MODEL / 4);
  convert_f2bf_kernel<<<(D_MODEL * D_MODEL / 4) / 256, blk, 0, stream>>>(wv, wvb, D_MODEL * D_MODEL / 4);
  convert_f2bf_kernel<<<(D_MODEL * D_MODEL / 4) / 256, blk, 0, stream>>>(wo, wob, D_MODEL * D_MODEL / 4);

  // Q = elu(x@Wq^T + bq)+1                       (M_TOK x 2048)
  gemm256_nt_kernel<0, false><<<dim3(D_MODEL / 256, M_TOK / 256), blk5, 0, stream>>>(
      xb, D_MODEL, wqb, D_MODEL, Qb, D_MODEL, bq, D_MODEL);
  // K^T = elu(Wk@x^T + bk)+1  (2048 x M_TOK), V^T = Wv@x^T + bv
  gemm256_nt_kernel<1, true><<<dim3(M_TOK / 256, D_MODEL / 256), blk5, 0, stream>>>(
      wkb, D_MODEL, xb, D_MODEL, KTb, M_TOK, bk, D_MODEL);
  gemm256_nt_kernel<2, true><<<dim3(M_TOK / 256, D_MODEL / 256), blk5, 0, stream>>>(
      wvb, D_MODEL, xb, D_MODEL, VTb, M_TOK, bv, D_MODEL);

  // KV^T per (b,h) via split-K partials + reduce
  kvt_partial_kernel<<<512, blk, 0, stream>>>(VTb, KTb, part);
  reduce_kvt_kernel<<<(NBH * DKH * DKH) / 256, blk, 0, stream>>>(part, KVTb);

  // K_sum and per-row denominators
  ksum_kernel<<<(NBH * DKH) / 4, blk, 0, stream>>>(KTb, ksum);
  qsum_kernel<<<(NBH * SEQ) / 4, blk, 0, stream>>>(Qb, ksum, qsum);

  // attn = (Q @ KV) / (Q . Ksum + 1e-8)   -> bf16 (aliases xb)
  qkv_kernel<<<dim3(1, SEQ / 128, NBH), blk, 0, stream>>>(Qb, KVTb, qsum, attn);

  // out = attn @ Wo^T + bo  -> fp32
  gemm256_nt_kernel<3, false><<<dim3(D_MODEL / 256, M_TOK / 256), blk5, 0, stream>>>(
      attn, D_MODEL, wob, D_MODEL, d_out, D_MODEL, bo, D_MODEL);
}

// Round 7
// 680.346 us; speedup vs baseline: 1.0310x; 1.0207x over previous
//
#include <hip/hip_runtime.h>

// Linear attention (elu+1 feature map), B=4 S=4096 D=2048 H=16 dk=128.
// bf16 MFMA, fp32 accumulate.
// Round 7: exact m201 8-phase/2-tile schedule for the 256x256 GEMM.
// 4 LDS slots (32KB = A 256x32 + B 256x32, XOR-swizzled). Tile 2i -> slots
// 0/1, tile 2i+1 -> slots 2/3. Per phase: 4 A ds_reads (+8 B in q0), 2 stage
// loads into strips retired by earlier phases, barrier, lgkm0+schedbar,
// setprio(1), 16 MFMA, setprio(0), barrier. vmcnt(6) only at ph3/ph7.
// Stage dribble: ph0: v.A-strips23 | ph1-2: w.B | ph3-4: w.A-strips | ph5-6:
// x.B | ph7: x.A-strips01  (w=2i+2, x=2i+3; x.As23 staged at next ph0).

#define D_MODEL 2048
#define SEQ     4096
#define BATCH   4
#define HEADS   16
#define DKH     128
#define M_TOK   16384   // BATCH*SEQ
#define NBH     64      // BATCH*HEADS

using frag8 = __attribute__((ext_vector_type(8))) short;   // 8 bf16 (4 VGPRs)
using f32x4 = __attribute__((ext_vector_type(4))) float;   // 4 fp32 acc

typedef __attribute__((address_space(1))) const unsigned int g_u32;
typedef __attribute__((address_space(3))) unsigned int       l_u32;

__device__ __forceinline__ unsigned short f2bf(float f) {
  unsigned u = __float_as_uint(f);
  u = u + 0x7fffu + ((u >> 16) & 1u);   // round-to-nearest-even
  return (unsigned short)(u >> 16);
}
__device__ __forceinline__ float bf2f(unsigned short h) {
  return __uint_as_float(((unsigned)h) << 16);
}

// ---- fp32 -> bf16 convert (vectorized) --------------------------------------
__global__ __launch_bounds__(256) void convert_f2bf_kernel(
    const float* __restrict__ in, unsigned short* __restrict__ out, int n4) {
  int i = blockIdx.x * 256 + threadIdx.x;
  if (i < n4) {
    float4 v = reinterpret_cast<const float4*>(in)[i];
    ushort4 o;
    o.x = f2bf(v.x); o.y = f2bf(v.y); o.z = f2bf(v.z); o.w = f2bf(v.w);
    reinterpret_cast<ushort4*>(out)[i] = o;
  }
}

// ============================================================================
// 256x256x(BK=64) 8-phase GEMM, C = A(256xK)*B(256xK)^T, bf16 NT.
// 512 thr = 8 waves (2M x 4N); per-wave C = 128x64 = 4 quadrants x 2m x 4n.
// Slot s (16384 elems = 32KB): A-part [0,8192) + B-part [8192,16384).
// Part layout: phys row p in [0,128) x 8 quads of 8 elems; logical row
// r = side*128+p (side = quad>>2), kcol group = quad&3; stored quad
// q' = quad ^ (p&7).  Reads: q' = (side*4+lh)^(lr&7).  Stage writes linear
// with source quad qd = (lane&7)^(lane>>3) (q' check: qd^(p&7)=lane&7 OK).
// ============================================================================

// stage one B half-slot (16KB, 2 loads/thread) into slot SLOT, k-col KC
#define ST_B(GB, LD, SLOT, KC)                                                \
  _Pragma("unroll") for (int j_ = 0; j_ < 2; ++j_)                            \
    __builtin_amdgcn_global_load_lds(                                         \
        (g_u32*)((GB) + (srow + wid * 16 + j_ * 8 + (lane >> 3)) * (LD)       \
                 + (KC) + scg * 8),                                           \
        (l_u32*)(sh + (SLOT) * 16384 + 8192 + (wid * 16 + j_ * 8) * 64),      \
        16, 0, 0);

// stage A strip ST (8KB: phys rows [32*ST,32*ST+32) of slots SP and SP+1)
#define ST_A(GA, LD, SP, ST, KC)                                              \
    __builtin_amdgcn_global_load_lds(                                         \
        (g_u32*)((GA) + (srow + (ST) * 32 + (wid & 3) * 8 + (lane >> 3)) * (LD) \
                 + (KC) + (wid >> 2) * 32 + scg * 8),                         \
        (l_u32*)(sh + ((SP) + (wid >> 2)) * 16384 +                           \
                 ((ST) * 32 + (wid & 3) * 8) * 64),                           \
        16, 0, 0);

#define RD_A(S0, S1, Q)                                                       \
  a0[0] = *(const frag8*)(lds + (S0) * 16384 + tA + (Q) * 2048);              \
  a0[1] = *(const frag8*)(lds + (S0) * 16384 + tA + (Q) * 2048 + 1024);       \
  a1[0] = *(const frag8*)(lds + (S1) * 16384 + tA + (Q) * 2048);              \
  a1[1] = *(const frag8*)(lds + (S1) * 16384 + tA + (Q) * 2048 + 1024);

#define RD_B(D0, D1, S0, S1)                                                  \
  _Pragma("unroll") for (int n_ = 0; n_ < 4; ++n_) {                          \
    D0[n_] = *(const frag8*)(lds + (S0) * 16384 + tB + n_ * 1024);            \
    D1[n_] = *(const frag8*)(lds + (S1) * 16384 + tB + n_ * 1024);            \
  }

#define MM8(AQ, B0, B1)                                                       \
  __builtin_amdgcn_s_setprio(1);                                              \
  _Pragma("unroll") for (int j_ = 0; j_ < 2; ++j_)                            \
  _Pragma("unroll") for (int n_ = 0; n_ < 4; ++n_)                            \
    acc[(AQ) + j_][n_] = __builtin_amdgcn_mfma_f32_16x16x32_bf16(             \
        a0[j_], B0[n_], acc[(AQ) + j_][n_], 0, 0, 0);                         \
  _Pragma("unroll") for (int j_ = 0; j_ < 2; ++j_)                            \
  _Pragma("unroll") for (int n_ = 0; n_ < 4; ++n_)                            \
    acc[(AQ) + j_][n_] = __builtin_amdgcn_mfma_f32_16x16x32_bf16(             \
        a1[j_], B1[n_], acc[(AQ) + j_][n_], 0, 0, 0);                         \
  __builtin_amdgcn_s_setprio(0);

#define BAR __builtin_amdgcn_s_barrier()
#define LG0                                                                   \
  asm volatile("s_waitcnt lgkmcnt(0)" ::: "memory");                          \
  __builtin_amdgcn_sched_barrier(0)

// MODE: 0 = elu(v+bias[col])+1 -> bf16   (Q projection)
//       1 = elu(v+bias[row])+1 -> bf16   (K^T projection)
//       2 = v+bias[row]        -> bf16   (V^T projection)
//       3 = v+bias[col]        -> f32    (final output projection)
template <int MODE, bool XMAJOR>
__global__ __launch_bounds__(512, 2) void gemm256_nt_kernel(
    const unsigned short* __restrict__ A, long lda,
    const unsigned short* __restrict__ Bm, long ldb,
    void* __restrict__ Cv, long ldc,
    const float* __restrict__ bias, int K) {
  __shared__ unsigned short sh[65536];   // 128 KiB = 4 slots
  const int lane = threadIdx.x & 63, wid = threadIdx.x >> 6;
  const int wm = wid >> 2, wn = wid & 3;
  const int lr = lane & 15, lh = lane >> 4;

  // T1 bijective XCD swizzle
  const int gx = gridDim.x, gy = gridDim.y;
  const int cpx = (gx * gy) >> 3;
  const int P = blockIdx.y * gx + blockIdx.x;
  const int Lw = (P & 7) * cpx + (P >> 3);
  int bx, by;
  if (XMAJOR) { bx = Lw / gy; by = Lw - bx * gy; }
  else        { by = Lw / gx; bx = Lw - by * gx; }

  const long m0 = (long)by * 256, n0 = (long)bx * 256;
  const unsigned short* Ablk = A + m0 * lda;
  const unsigned short* Bblk = Bm + n0 * ldb;
  const int NT = K >> 6;

  // read-side thread constants
  const int qA = (wm * 4 + lh) ^ (lr & 7);
  const int qB = ((wn >> 1) * 4 + lh) ^ (lr & 7);
  const unsigned short* lds = sh;
  const int tA = lr * 64 + qA * 8;
  const int tB = 8192 + ((wn & 1) * 64 + lr) * 64 + qB * 8;

  // stage-side thread constants
  const int sqd = (lane & 7) ^ (lane >> 3);
  const int scg = sqd & 3;
  const long srow = (long)((sqd >> 2) * 128);

  f32x4 acc[8][4];
#pragma unroll
  for (int m = 0; m < 8; ++m)
#pragma unroll
    for (int n = 0; n < 4; ++n) acc[m][n] = (f32x4){0.f, 0.f, 0.f, 0.f};

  frag8 a0[2], a1[2], bu0[4], bu1[4], bv0[4], bv1[4];

  // prologue: tile 0 complete (8 units), tile 1 all but A-strips 2,3 (6 units)
  ST_B(Bblk, ldb, 0, 0)
  ST_B(Bblk, ldb, 1, 32)
  ST_A(Ablk, lda, 0, 0, 0) ST_A(Ablk, lda, 0, 1, 0)
  ST_A(Ablk, lda, 0, 2, 0) ST_A(Ablk, lda, 0, 3, 0)
  if (NT > 1) {
    ST_B(Bblk, ldb, 2, 64)
    ST_B(Bblk, ldb, 3, 96)
    ST_A(Ablk, lda, 2, 0, 64) ST_A(Ablk, lda, 2, 1, 64)
  }
  asm volatile("s_waitcnt vmcnt(6)" ::: "memory");   // tile 0 landed
  BAR;

  const int NI = NT >> 1;
  for (int i = 0; i < NI; ++i) {
    const int kv = i * 128 + 64, kw = i * 128 + 128, kx = i * 128 + 192;
    const bool wok = (i + 1) < NI;
    // ---- ph0: tile u (slots 0,1) quadrant 0 ----
    RD_A(0, 1, 0)
    RD_B(bu0, bu1, 0, 1)
    ST_A(Ablk, lda, 2, 2, kv) ST_A(Ablk, lda, 2, 3, kv)
    asm volatile("s_waitcnt lgkmcnt(8)" ::: "memory");
    BAR; LG0;
    MM8(0, bu0, bu1)
    BAR;
    // ---- ph1: u q1 ----
    RD_A(0, 1, 1)
    if (wok) { ST_B(Bblk, ldb, 0, kw) }
    BAR; LG0;
    MM8(2, bu0, bu1)
    BAR;
    // ---- ph2: u q2 ----
    RD_A(0, 1, 2)
    if (wok) { ST_B(Bblk, ldb, 1, kw + 32) }
    BAR; LG0;
    MM8(4, bu0, bu1)
    BAR;
    // ---- ph3: u q3 ; vmcnt gate for tile v ----
    RD_A(0, 1, 3)
    if (wok) { ST_A(Ablk, lda, 0, 0, kw) ST_A(Ablk, lda, 0, 1, kw) }
    if (wok) asm volatile("s_waitcnt vmcnt(6)" ::: "memory");
    else     asm volatile("s_waitcnt vmcnt(0)" ::: "memory");
    BAR; LG0;
    MM8(6, bu0, bu1)
    BAR;
    // ---- ph4: tile v (slots 2,3) quadrant 0 ----
    RD_A(2, 3, 0)
    RD_B(bv0, bv1, 2, 3)
    if (wok) { ST_A(Ablk, lda, 0, 2, kw) ST_A(Ablk, lda, 0, 3, kw) }
    asm volatile("s_waitcnt lgkmcnt(8)" ::: "memory");
    BAR; LG0;
    MM8(0, bv0, bv1)
    BAR;
    // ---- ph5: v q1 ----
    RD_A(2, 3, 1)
    if (wok) { ST_B(Bblk, ldb, 2, kx) }
    BAR; LG0;
    MM8(2, bv0, bv1)
    BAR;
    // ---- ph6: v q2 ----
    RD_A(2, 3, 2)
    if (wok) { ST_B(Bblk, ldb, 3, kx + 32) }
    BAR; LG0;
    MM8(4, bv0, bv1)
    BAR;
    // ---- ph7: v q3 ; vmcnt gate for tile w (next iter) ----
    RD_A(2, 3, 3)
    if (wok) { ST_A(Ablk, lda, 2, 0, kx) ST_A(Ablk, lda, 2, 1, kx)
               asm volatile("s_waitcnt vmcnt(6)" ::: "memory"); }
    BAR; LG0;
    MM8(6, bv0, bv1)
    BAR;
  }

  // epilogue: acc[m] (m = 2q+j) -> rows wm*128 + q*32 + j*16
#pragma unroll
  for (int m = 0; m < 8; ++m)
#pragma unroll
    for (int n = 0; n < 4; ++n)
#pragma unroll
      for (int r = 0; r < 4; ++r) {
        long row = m0 + wm * 128 + (m >> 1) * 32 + (m & 1) * 16 + lh * 4 + r;
        long col = n0 + wn * 64 + n * 16 + lr;
        float v = acc[m][n][r];
        if (MODE == 0) {
          v += bias[col]; v = v > 0.f ? v + 1.f : __expf(v);
          ((unsigned short*)Cv)[row * ldc + col] = f2bf(v);
        } else if (MODE == 1) {
          v += bias[row]; v = v > 0.f ? v + 1.f : __expf(v);
          ((unsigned short*)Cv)[row * ldc + col] = f2bf(v);
        } else if (MODE == 2) {
          v += bias[row];
          ((unsigned short*)Cv)[row * ldc + col] = f2bf(v);
        } else {
          v += bias[col];
          ((float*)Cv)[row * ldc + col] = v;
        }
      }
}

// ============================================================================
// 128x128 path (attention core) — unchanged.
// ============================================================================
__device__ __forceinline__ void stage_tile(const unsigned short* __restrict__ G,
                                           long ld, unsigned short* __restrict__ L) {
  const int w = threadIdx.x >> 6, l = threadIdx.x & 63;
#pragma unroll
  for (int r = 0; r < 4; ++r) {
    const int chunk = w * 4 + r;
    const int row = chunk * 8 + (l >> 3);
    const int col = (l & 7) * 8;
    __builtin_amdgcn_global_load_lds((g_u32*)(G + (long)row * ld + col),
                                     (l_u32*)(L + chunk * 512), 16, 0, 0);
  }
}

__device__ __forceinline__ void gemm_mainloop(const unsigned short* __restrict__ A, long lda,
                                              const unsigned short* __restrict__ B, long ldb,
                                              int K, unsigned short* lA, unsigned short* lB,
                                              f32x4 acc[4][4]) {
  const int lane = threadIdx.x & 63;
  const int wid  = threadIdx.x >> 6;
  const int wr = wid >> 1, wc = wid & 1;
  const int lr = lane & 15, lh = lane >> 4;
  for (int k0 = 0; k0 < K; k0 += 64) {
    stage_tile(A + k0, lda, lA);
    stage_tile(B + k0, ldb, lB);
    __syncthreads();
#pragma unroll
    for (int kk = 0; kk < 64; kk += 32) {
      frag8 av[4], bv[4];
#pragma unroll
      for (int m = 0; m < 4; ++m)
        av[m] = *reinterpret_cast<const frag8*>(lA + (wr * 64 + m * 16 + lr) * 64 + kk + lh * 8);
#pragma unroll
      for (int n = 0; n < 4; ++n)
        bv[n] = *reinterpret_cast<const frag8*>(lB + (wc * 64 + n * 16 + lr) * 64 + kk + lh * 8);
#pragma unroll
      for (int m = 0; m < 4; ++m)
#pragma unroll
        for (int n = 0; n < 4; ++n)
          acc[m][n] = __builtin_amdgcn_mfma_f32_16x16x32_bf16(av[m], bv[n], acc[m][n], 0, 0, 0);
    }
    __syncthreads();
  }
}

#define ACC_INIT(acc)                                   \
  _Pragma("unroll") for (int m_ = 0; m_ < 4; ++m_)      \
  _Pragma("unroll") for (int n_ = 0; n_ < 4; ++n_)      \
      acc[m_][n_] = (f32x4){0.f, 0.f, 0.f, 0.f};

// ---- KV^T partials: per (bh, chunk) C[e,d] = sum_t V[t,e]K[t,d] over 512 t --
__global__ __launch_bounds__(256) void kvt_partial_kernel(
    const unsigned short* __restrict__ VT, const unsigned short* __restrict__ KT,
    float* __restrict__ part) {
  __shared__ unsigned short lA[128 * 64], lB[128 * 64];
  const int z = blockIdx.x;            // 0..511 = bh*8 + chunk
  const int bh = z >> 3, c = z & 7;
  const int b = bh >> 4, h = bh & 15;
  const long tOff = (long)b * SEQ + (long)c * 512;
  const unsigned short* A  = VT + (long)(h * DKH) * M_TOK + tOff;
  const unsigned short* Bm = KT + (long)(h * DKH) * M_TOK + tOff;
  f32x4 acc[4][4];
  ACC_INIT(acc);
  gemm_mainloop(A, M_TOK, Bm, M_TOK, 512, lA, lB, acc);
  const int lane = threadIdx.x & 63, wid = threadIdx.x >> 6;
  const int wr = wid >> 1, wc = wid & 1, lr = lane & 15, lh = lane >> 4;
  float* out = part + (long)z * (DKH * DKH);
#pragma unroll
  for (int m = 0; m < 4; ++m)
#pragma unroll
    for (int n = 0; n < 4; ++n)
#pragma unroll
      for (int r = 0; r < 4; ++r) {
        int row = wr * 64 + m * 16 + lh * 4 + r;   // e
        int col = wc * 64 + n * 16 + lr;           // d
        out[row * DKH + col] = acc[m][n][r];
      }
}

__global__ __launch_bounds__(256) void reduce_kvt_kernel(
    const float* __restrict__ part, unsigned short* __restrict__ kvt) {
  int i = blockIdx.x * 256 + threadIdx.x;          // over 64*16384
  if (i < NBH * DKH * DKH) {
    int bh = i >> 14, j = i & 16383;
    float s = 0.f;
#pragma unroll
    for (int c = 0; c < 8; ++c) s += part[(((long)bh * 8 + c) << 14) + j];
    kvt[i] = f2bf(s);
  }
}

// ---- K row sums ------------------------------------------------------------
__global__ __launch_bounds__(256) void ksum_kernel(const unsigned short* __restrict__ KT,
                                                   float* __restrict__ ksum) {
  int gr = blockIdx.x * 4 + (threadIdx.x >> 6);    // 0..8191 = bh*128+d
  int lane = threadIdx.x & 63;
  int bh = gr >> 7, d = gr & 127;
  int b = bh >> 4, h = bh & 15;
  const unsigned short* p = KT + (long)(h * DKH + d) * M_TOK + (long)b * SEQ;
  float s = 0.f;
#pragma unroll
  for (int i = 0; i < 8; ++i) {
    uint4 v = *reinterpret_cast<const uint4*>(p + (i * 64 + lane) * 8);
    unsigned w[4] = {v.x, v.y, v.z, v.w};
#pragma unroll
    for (int j = 0; j < 4; ++j) {
      s += bf2f((unsigned short)(w[j] & 0xffff));
      s += bf2f((unsigned short)(w[j] >> 16));
    }
  }
#pragma unroll
  for (int o = 32; o > 0; o >>= 1) s += __shfl_down(s, o);
  if (lane == 0) ksum[gr] = s;
}

// ---- qsum ------------------------------------------------------------------
__global__ __launch_bounds__(256) void qsum_kernel(const unsigned short* __restrict__ Q,
                                                   const float* __restrict__ ksum,
                                                   float* __restrict__ qsum) {
  int gr = blockIdx.x * 4 + (threadIdx.x >> 6);    // 0..262143 = bh*4096 + s
  int lane = threadIdx.x & 63;
  int bh = gr >> 12, s = gr & 4095;
  int b = bh >> 4, h = bh & 15;
  const unsigned short* q = Q + ((long)b * SEQ + s) * D_MODEL + h * DKH + lane * 2;
  unsigned u = *reinterpret_cast<const unsigned*>(q);
  const float* ks = ksum + bh * DKH + lane * 2;
  float sum = bf2f((unsigned short)(u & 0xffff)) * ks[0] +
              bf2f((unsigned short)(u >> 16)) * ks[1];
#pragma unroll
  for (int o = 32; o > 0; o >>= 1) sum += __shfl_down(sum, o);
  if (lane == 0) qsum[gr] = sum;
}

// ---- QKV -------------------------------------------------------------------
__global__ __launch_bounds__(256) void qkv_kernel(const unsigned short* __restrict__ Q,
                                                  const unsigned short* __restrict__ KVT,
                                                  const float* __restrict__ qsum,
                                                  unsigned short* __restrict__ attn) {
  __shared__ unsigned short lA[128 * 64], lB[128 * 64];
  const int z = blockIdx.z, b = z >> 4, h = z & 15;
  const long m0 = (long)blockIdx.y * 128;
  const unsigned short* A  = Q + ((long)b * SEQ + m0) * D_MODEL + h * DKH;
  const unsigned short* Bm = KVT + (long)z * (DKH * DKH);
  f32x4 acc[4][4];
  ACC_INIT(acc);
  gemm_mainloop(A, D_MODEL, Bm, DKH, DKH, lA, lB, acc);
  const int lane = threadIdx.x & 63, wid = threadIdx.x >> 6;
  const int wr = wid >> 1, wc = wid & 1, lr = lane & 15, lh = lane >> 4;
#pragma unroll
  for (int m = 0; m < 4; ++m)
#pragma unroll
    for (int n = 0; n < 4; ++n)
#pragma unroll
      for (int r = 0; r < 4; ++r) {
        long row = m0 + wr * 64 + m * 16 + lh * 4 + r;   // s in [0,4096)
        int  col = wc * 64 + n * 16 + lr;                // e in [0,128)
        float dnm = qsum[(long)z * SEQ + row] + 1e-8f;
        float v = acc[m][n][r] / dnm;
        attn[((long)b * SEQ + row) * D_MODEL + h * DKH + col] = f2bf(v);
      }
}

// ---- workspace layout (bytes) ----------------------------------------------
#define OFF_XB   0L
#define OFF_WQ   (OFF_XB + (long)M_TOK * D_MODEL * 2)
#define OFF_WK   (OFF_WQ + (long)D_MODEL * D_MODEL * 2)
#define OFF_WV   (OFF_WK + (long)D_MODEL * D_MODEL * 2)
#define OFF_WO   (OFF_WV + (long)D_MODEL * D_MODEL * 2)
#define OFF_QB   (OFF_WO + (long)D_MODEL * D_MODEL * 2)
#define OFF_KT   (OFF_QB + (long)M_TOK * D_MODEL * 2)
#define OFF_VT   (OFF_KT + (long)M_TOK * D_MODEL * 2)
#define OFF_PART (OFF_VT + (long)M_TOK * D_MODEL * 2)
#define OFF_KVT  (OFF_PART + (long)512 * DKH * DKH * 4)
#define OFF_KSUM (OFF_KVT + (long)NBH * DKH * DKH * 2)
#define OFF_QSUM (OFF_KSUM + (long)NBH * DKH * 4)
#define OFF_ATTN OFF_XB   // alias: x_bf16 dead after V^T projection

extern "C" void kernel_launch(void* const* d_in, const int* in_sizes, int n_in,
                              void* d_out, int out_size, void* d_ws, size_t ws_size,
                              hipStream_t stream) {
  const float* x  = (const float*)d_in[0];
  const float* wq = (const float*)d_in[1];
  const float* bq = (const float*)d_in[2];
  const float* wk = (const float*)d_in[3];
  const float* bk = (const float*)d_in[4];
  const float* wv = (const float*)d_in[5];
  const float* bv = (const float*)d_in[6];
  const float* wo = (const float*)d_in[7];
  const float* bo = (const float*)d_in[8];

  char* ws = (char*)d_ws;
  unsigned short* xb   = (unsigned short*)(ws + OFF_XB);
  unsigned short* wqb  = (unsigned short*)(ws + OFF_WQ);
  unsigned short* wkb  = (unsigned short*)(ws + OFF_WK);
  unsigned short* wvb  = (unsigned short*)(ws + OFF_WV);
  unsigned short* wob  = (unsigned short*)(ws + OFF_WO);
  unsigned short* Qb   = (unsigned short*)(ws + OFF_QB);
  unsigned short* KTb  = (unsigned short*)(ws + OFF_KT);
  unsigned short* VTb  = (unsigned short*)(ws + OFF_VT);
  float*          part = (float*)(ws + OFF_PART);
  unsigned short* KVTb = (unsigned short*)(ws + OFF_KVT);
  float*          ksum = (float*)(ws + OFF_KSUM);
  float*          qsum = (float*)(ws + OFF_QSUM);
  unsigned short* attn = (unsigned short*)(ws + OFF_ATTN);

  dim3 blk(256);
  dim3 blk5(512);

  // fp32 -> bf16
  convert_f2bf_kernel<<<(M_TOK * D_MODEL / 4) / 256, blk, 0, stream>>>(x, xb, M_TOK * D_MODEL / 4);
  convert_f2bf_kernel<<<(D_MODEL * D_MODEL / 4) / 256, blk, 0, stream>>>(wq, wqb, D_MODEL * D_MODEL / 4);
  convert_f2bf_kernel<<<(D_MODEL * D_MODEL / 4) / 256, blk, 0, stream>>>(wk, wkb, D_MODEL * D_MODEL / 4);
  convert_f2bf_kernel<<<(D_MODEL * D_MODEL / 4) / 256, blk, 0, stream>>>(wv, wvb, D_MODEL * D_MODEL / 4);
  convert_f2bf_kernel<<<(D_MODEL * D_MODEL / 4) / 256, blk, 0, stream>>>(wo, wob, D_MODEL * D_MODEL / 4);

  // Q = elu(x@Wq^T + bq)+1                       (M_TOK x 2048)
  gemm256_nt_kernel<0, false><<<dim3(D_MODEL / 256, M_TOK / 256), blk5, 0, stream>>>(
      xb, D_MODEL, wqb, D_MODEL, Qb, D_MODEL, bq, D_MODEL);
  // K^T = elu(Wk@x^T + bk)+1  (2048 x M_TOK), V^T = Wv@x^T + bv
  gemm256_nt_kernel<1, true><<<dim3(M_TOK / 256, D_MODEL / 256), blk5, 0, stream>>>(
      wkb, D_MODEL, xb, D_MODEL, KTb, M_TOK, bk, D_MODEL);
  gemm256_nt_kernel<2, true><<<dim3(M_TOK / 256, D_MODEL / 256), blk5, 0, stream>>>(
      wvb, D_MODEL, xb, D_MODEL, VTb, M_TOK, bv, D_MODEL);

  // KV^T per (b,h) via split-K partials + reduce
  kvt_partial_kernel<<<512, blk, 0, stream>>>(VTb, KTb, part);
  reduce_kvt_kernel<<<(NBH * DKH * DKH) / 256, blk, 0, stream>>>(part, KVTb);

  // K_sum and per-row denominators
  ksum_kernel<<<(NBH * DKH) / 4, blk, 0, stream>>>(KTb, ksum);
  qsum_kernel<<<(NBH * SEQ) / 4, blk, 0, stream>>>(Qb, ksum, qsum);

  // attn = (Q @ KV) / (Q . Ksum + 1e-8)   -> bf16 (aliases xb)
  qkv_kernel<<<dim3(1, SEQ / 128, NBH), blk, 0, stream>>>(Qb, KVTb, qsum, attn);

  // out = attn @ Wo^T + bo  -> fp32
  gemm256_nt_kernel<3, false><<<dim3(D_MODEL / 256, M_TOK / 256), blk5, 0, stream>>>(
      attn, D_MODEL, wob, D_MODEL, d_out, D_MODEL, bo, D_MODEL);
}